// Round 2
// baseline (36807.773 us; speedup 1.0000x reference)
//
#include <hip/hip_runtime.h>
#include <cmath>

// ---------------------------------------------------------------------------
// VQ-VAE forward for MI355X. All fp32 direct convolutions, thread-per-output,
// oc mapped to blockIdx.y so weight loads are wave-uniform (scalar loads).
// VQ is fused with the 1x1 pre-VQ conv; loss/perplexity via block reductions
// + global atomics, finalized in a tiny kernel.
//
// ROUND 1 FIX: previous version assumed >=302 MiB of d_ws and faulted when
// ws_size was smaller. Now the batch is processed in chunks sized from
// ws_size at launch time (per-sample scratch = 2,359,296 floats = 9 MiB).
// ---------------------------------------------------------------------------

static constexpr int NPOS  = 131072;        // 32 * 64 * 64 positions at VQ
static constexpr long long NELEM = 8388608; // NPOS * 64

// ---- generic direct conv ---------------------------------------------------
// WMODE 0: weights OIHW (oc,ic,ky,kx). WMODE 1: transposed-conv stride-1 form,
// weights are (ic,oc,ky,kx) and kernel is flipped (equivalent conv, pad=K-1-p).
template<int IC, int OC, int KK, int S, int P, int WMODE, bool BIAS, bool RELU_IN, bool RELU_OUT>
__global__ void __launch_bounds__(256) conv2d_k(
    const float* __restrict__ in, const float* __restrict__ w,
    const float* __restrict__ bias, float* __restrict__ out,
    int IH, int IW, int OH, int OW)
{
  int p = blockIdx.x * 256 + threadIdx.x;
  if (p >= OH * OW) return;
  int oc = blockIdx.y;
  int b  = blockIdx.z;
  int oy = p / OW, ox = p - oy * OW;

  float acc = BIAS ? bias[oc] : 0.f;
  const float* inb = in + (size_t)b * IC * IH * IW;

  for (int ic = 0; ic < IC; ++ic) {
    const float* inp = inb + (size_t)ic * IH * IW;
    #pragma unroll
    for (int ky = 0; ky < KK; ++ky) {
      int iy = oy * S - P + ky;
      if (iy < 0 || iy >= IH) continue;
      #pragma unroll
      for (int kx = 0; kx < KK; ++kx) {
        int ix = ox * S - P + kx;
        if (ix < 0 || ix >= IW) continue;
        float v = inp[iy * IW + ix];
        if (RELU_IN) v = fmaxf(v, 0.f);
        float wt = (WMODE == 0)
          ? w[((oc * IC + ic) * KK + ky) * KK + kx]
          : w[((ic * OC + oc) * KK + (KK - 1 - ky)) * KK + (KK - 1 - kx)];
        acc += v * wt;
      }
    }
  }
  if (RELU_OUT) acc = fmaxf(acc, 0.f);
  out[((size_t)(b * OC + oc) * OH + oy) * OW + ox] = acc;
}

// ---- residual tail: out = relu(x) + w2 @ h (1x1 conv, no bias) -------------
// x: (c,128,64,64) pre-relu skip;  h: (c,64,64,64);  w2: (128,64)
__global__ void __launch_bounds__(256) res_add_k(
    const float* __restrict__ x, const float* __restrict__ h,
    const float* __restrict__ w2, float* __restrict__ out)
{
  int p  = blockIdx.x * 256 + threadIdx.x;   // position in 64x64 plane
  int oc = blockIdx.y;
  int b  = blockIdx.z;
  size_t n = ((size_t)(b * 128 + oc)) * 4096 + p;
  float acc = fmaxf(x[n], 0.f);
  const float* hb = h + (size_t)b * 64 * 4096 + p;
  #pragma unroll 8
  for (int ic = 0; ic < 64; ++ic)
    acc += w2[oc * 64 + ic] * hb[(size_t)ic * 4096];
  out[n] = acc;
}

// ---- stride-2 k=4 transposed conv ------------------------------------------
// w: (IC, OC, 4, 4) torch ConvTranspose2d layout. pad=1, stride=2.
template<int IC, int OC, bool RELU_IN, bool RELU_OUT, bool TANH_OUT>
__global__ void __launch_bounds__(256) deconv2_k(
    const float* __restrict__ in, const float* __restrict__ w,
    const float* __restrict__ bias, float* __restrict__ out,
    int IH, int IW, int OH, int OW)
{
  int p = blockIdx.x * 256 + threadIdx.x;
  if (p >= OH * OW) return;
  int oc = blockIdx.y;
  int b  = blockIdx.z;
  int oy = p / OW, ox = p - oy * OW;

  int ky0 = (oy + 1) & 1;
  int iy0 = (oy + 1 - ky0) >> 1;
  int ky1 = ky0 + 2;
  int iy1 = iy0 - 1;
  bool vy0 = (iy0 >= 0 && iy0 < IH);
  bool vy1 = (iy1 >= 0 && iy1 < IH);
  int kx0 = (ox + 1) & 1;
  int ix0 = (ox + 1 - kx0) >> 1;
  int kx1 = kx0 + 2;
  int ix1 = ix0 - 1;
  bool vx0 = (ix0 >= 0 && ix0 < IW);
  bool vx1 = (ix1 >= 0 && ix1 < IW);

  float acc = bias[oc];
  const float* inb = in + (size_t)b * IC * IH * IW;
  for (int ic = 0; ic < IC; ++ic) {
    const float* inp = inb + (size_t)ic * IH * IW;
    const float* wp  = w + ((size_t)ic * OC + oc) * 16;
    if (vy0 && vx0) { float t = inp[iy0 * IW + ix0]; if (RELU_IN) t = fmaxf(t, 0.f); acc += t * wp[ky0 * 4 + kx0]; }
    if (vy0 && vx1) { float t = inp[iy0 * IW + ix1]; if (RELU_IN) t = fmaxf(t, 0.f); acc += t * wp[ky0 * 4 + kx1]; }
    if (vy1 && vx0) { float t = inp[iy1 * IW + ix0]; if (RELU_IN) t = fmaxf(t, 0.f); acc += t * wp[ky1 * 4 + kx0]; }
    if (vy1 && vx1) { float t = inp[iy1 * IW + ix1]; if (RELU_IN) t = fmaxf(t, 0.f); acc += t * wp[ky1 * 4 + kx1]; }
  }
  if (RELU_OUT) acc = fmaxf(acc, 0.f);
  if (TANH_OUT) acc = tanhf(acc);
  out[((size_t)(b * OC + oc) * OH + oy) * OW + ox] = acc;
}

// ---- fused pre-VQ 1x1 conv + vector quantization ---------------------------
// xres: (c,128,64,64) pre-relu. vw: (64,128). vb: (64). emb: (64,64).
// qn out: (c,64,64,64) NCHW (chunk-offset base). npos = c*4096.
__global__ void __launch_bounds__(256) vq_k(
    const float* __restrict__ xres, const float* __restrict__ vw,
    const float* __restrict__ vb, const float* __restrict__ emb,
    float* __restrict__ qn, float* __restrict__ sum_sq, int* __restrict__ hist)
{
  int tid = threadIdx.x;
  int n = blockIdx.x * 256 + tid;
  int b = n >> 12;
  int pos = n & 4095;

  float z[64];
  #pragma unroll
  for (int k = 0; k < 64; ++k) z[k] = vb[k];

  const float* xb = xres + (size_t)b * 128 * 4096 + pos;
  for (int c = 0; c < 128; ++c) {
    float v = fmaxf(xb[(size_t)c * 4096], 0.f);
    #pragma unroll
    for (int k = 0; k < 64; ++k) z[k] += v * vw[k * 128 + c];
  }

  float z2 = 0.f;
  #pragma unroll
  for (int d = 0; d < 64; ++d) z2 += z[d] * z[d];

  float best = INFINITY;
  int bidx = 0;
  for (int k = 0; k < 64; ++k) {
    float dot = 0.f, e2 = 0.f;
    #pragma unroll
    for (int d = 0; d < 64; ++d) {
      float e = emb[k * 64 + d];
      dot += z[d] * e;
      e2  += e * e;
    }
    float dist = z2 + e2 - 2.f * dot;     // matches reference formula
    if (dist < best) { best = dist; bidx = k; }
  }

  float sq = 0.f;
  const float* eb = emb + bidx * 64;
  float* qb = qn + (size_t)b * 64 * 4096 + pos;
  #pragma unroll
  for (int d = 0; d < 64; ++d) {
    float e = eb[d];
    float df = e - z[d];
    sq += df * df;
    qb[(size_t)d * 4096] = e;
  }

  __shared__ float red[256];
  __shared__ int lh[64];
  red[tid] = sq;
  if (tid < 64) lh[tid] = 0;
  __syncthreads();
  atomicAdd(&lh[bidx], 1);
  for (int s = 128; s > 0; s >>= 1) {
    if (tid < s) red[tid] += red[tid + s];
    __syncthreads();
  }
  if (tid == 0) atomicAdd(sum_sq, red[0]);
  if (tid < 64) atomicAdd(&hist[tid], lh[tid]);
}

// ---- scratch init + scalar finalize ----------------------------------------
__global__ void init_k(float* sum_sq, int* hist)
{
  int t = threadIdx.x;
  if (t == 0) sum_sq[0] = 0.f;
  if (t < 64) hist[t] = 0;
}

__global__ void finalize_k(const float* __restrict__ sum_sq, const int* __restrict__ hist,
                           float* __restrict__ loss_out, float* __restrict__ perp_out)
{
  if (threadIdx.x == 0) {
    float mse = sum_sq[0] / (float)NELEM;
    loss_out[0] = 1.25f * mse;               // beta*commit + embedding, equal in fwd
    float ent = 0.f;
    for (int k = 0; k < 64; ++k) {
      float p = (float)hist[k] / (float)NPOS;
      ent += p * logf(p + 1e-10f);
    }
    perp_out[0] = expf(-ent);
  }
}

// ---------------------------------------------------------------------------
extern "C" void kernel_launch(void* const* d_in, const int* in_sizes, int n_in,
                              void* d_out, int out_size, void* d_ws, size_t ws_size,
                              hipStream_t stream)
{
  const float* x        = (const float*)d_in[0];
  const float* enc_c1_w = (const float*)d_in[1];
  const float* enc_c1_b = (const float*)d_in[2];
  const float* enc_c2_w = (const float*)d_in[3];
  const float* enc_c2_b = (const float*)d_in[4];
  const float* enc_c3_w = (const float*)d_in[5];
  const float* enc_c3_b = (const float*)d_in[6];
  const float* enc_r1_w = (const float*)d_in[7];
  const float* enc_r2_w = (const float*)d_in[8];
  const float* vqc_w    = (const float*)d_in[9];
  const float* vqc_b    = (const float*)d_in[10];
  const float* emb      = (const float*)d_in[11];
  const float* dec_c1_w = (const float*)d_in[12];
  const float* dec_c1_b = (const float*)d_in[13];
  const float* dec_r1_w = (const float*)d_in[14];
  const float* dec_r2_w = (const float*)d_in[15];
  const float* dec_c2_w = (const float*)d_in[16];
  const float* dec_c2_b = (const float*)d_in[17];
  const float* dec_c3_w = (const float*)d_in[18];
  const float* dec_c3_b = (const float*)d_in[19];

  // output layout: [loss(1)] [x_re(32*1*256*256)] [perplexity(1)] [qn(32*64*64*64)]
  float* out      = (float*)d_out;
  float* loss_out = out;
  float* xre_out  = out + 1;
  float* perp_out = out + 1 + 2097152;
  float* qn_out   = out + 2 + 2097152;

  // ---- workspace: scalars first, then chunk-sized ping-pong buffers ----
  float* sum_sq = (float*)d_ws;               // 1 float
  int*   hist   = (int*)d_ws + 1;             // 64 ints
  float* base   = (float*)d_ws + 256;         // aligned region for activations

  // per-sample scratch floats: A(64*128*128)=1048576, B=C(128*64*64)=524288,
  // D(64*64*64)=262144  => 2,359,296 floats (9 MiB)
  const size_t PER_A = 1048576, PER_B = 524288, PER_D = 262144;
  const size_t PER_SAMPLE = PER_A + 2 * PER_B + PER_D;

  long long avail = (long long)(ws_size / 4) - 256;
  int chunk = (int)(avail / (long long)PER_SAMPLE);
  if (chunk > 32) chunk = 32;
  if (chunk < 1)  chunk = 1;   // below ~9 MiB of ws nothing fits; best effort

  hipLaunchKernelGGL(init_k, dim3(1), dim3(128), 0, stream, sum_sq, hist);

  for (int b0 = 0; b0 < 32; b0 += chunk) {
    int cur = (32 - b0 < chunk) ? (32 - b0) : chunk;

    float* A = base;                       // cur * 1048576  (c,64,128,128)
    float* B = A + (size_t)chunk * PER_A;  // cur * 524288   (c,128,64,64)
    float* C = B + (size_t)chunk * PER_B;  // cur * 524288   (c,128,64,64)
    float* D = C + (size_t)chunk * PER_B;  // cur * 262144   (c,64,64,64)

    const float* xC  = x + (size_t)b0 * 65536;
    float* qnC  = qn_out + (size_t)b0 * 262144;
    float* xreC = xre_out + (size_t)b0 * 65536;

    // ---- encoder ----
    hipLaunchKernelGGL((conv2d_k<1, 64, 4, 2, 1, 0, true, false, true>),
                       dim3(64, 64, cur), dim3(256), 0, stream,
                       xC, enc_c1_w, enc_c1_b, A, 256, 256, 128, 128);
    hipLaunchKernelGGL((conv2d_k<64, 128, 4, 2, 1, 0, true, false, true>),
                       dim3(16, 128, cur), dim3(256), 0, stream,
                       A, enc_c2_w, enc_c2_b, B, 128, 128, 64, 64);
    hipLaunchKernelGGL((conv2d_k<128, 128, 3, 1, 1, 0, true, false, false>),
                       dim3(16, 128, cur), dim3(256), 0, stream,
                       B, enc_c3_w, enc_c3_b, C, 64, 64, 64, 64);

    // encoder residual block (2 iterations, shared weights)
    hipLaunchKernelGGL((conv2d_k<128, 64, 3, 1, 1, 0, false, true, true>),
                       dim3(16, 64, cur), dim3(256), 0, stream,
                       C, enc_r1_w, nullptr, D, 64, 64, 64, 64);
    hipLaunchKernelGGL(res_add_k, dim3(16, 128, cur), dim3(256), 0, stream,
                       C, D, enc_r2_w, B);
    hipLaunchKernelGGL((conv2d_k<128, 64, 3, 1, 1, 0, false, true, true>),
                       dim3(16, 64, cur), dim3(256), 0, stream,
                       B, enc_r1_w, nullptr, D, 64, 64, 64, 64);
    hipLaunchKernelGGL(res_add_k, dim3(16, 128, cur), dim3(256), 0, stream,
                       B, D, enc_r2_w, C);

    // ---- fused pre-VQ conv + VQ (applies final res relu on read) ----
    hipLaunchKernelGGL(vq_k, dim3(cur * 16), dim3(256), 0, stream,
                       C, vqc_w, vqc_b, emb, qnC, sum_sq, hist);

    // ---- decoder ----
    hipLaunchKernelGGL((conv2d_k<64, 128, 3, 1, 1, 1, true, false, false>),
                       dim3(16, 128, cur), dim3(256), 0, stream,
                       qnC, dec_c1_w, dec_c1_b, B, 64, 64, 64, 64);

    hipLaunchKernelGGL((conv2d_k<128, 64, 3, 1, 1, 0, false, true, true>),
                       dim3(16, 64, cur), dim3(256), 0, stream,
                       B, dec_r1_w, nullptr, D, 64, 64, 64, 64);
    hipLaunchKernelGGL(res_add_k, dim3(16, 128, cur), dim3(256), 0, stream,
                       B, D, dec_r2_w, C);
    hipLaunchKernelGGL((conv2d_k<128, 64, 3, 1, 1, 0, false, true, true>),
                       dim3(16, 64, cur), dim3(256), 0, stream,
                       C, dec_r1_w, nullptr, D, 64, 64, 64, 64);
    hipLaunchKernelGGL(res_add_k, dim3(16, 128, cur), dim3(256), 0, stream,
                       C, D, dec_r2_w, B);

    // dec_c2 applies the final residual relu on read
    hipLaunchKernelGGL((deconv2_k<128, 64, true, true, false>),
                       dim3(64, 64, cur), dim3(256), 0, stream,
                       B, dec_c2_w, dec_c2_b, A, 64, 64, 128, 128);
    hipLaunchKernelGGL((deconv2_k<64, 1, false, false, true>),
                       dim3(256, 1, cur), dim3(256), 0, stream,
                       A, dec_c3_w, dec_c3_b, xreC, 128, 128, 256, 256);
  }

  hipLaunchKernelGGL(finalize_k, dim3(1), dim3(64), 0, stream,
                     sum_sq, hist, loss_out, perp_out);
}

// Round 3
// 9884.055 us; speedup vs baseline: 3.7240x; 3.7240x over previous
//
#include <hip/hip_runtime.h>
#include <cmath>

// ---------------------------------------------------------------------------
// VQ-VAE forward, round 3: register-tiled + LDS-staged fp32 convolutions.
// Round-2 rocprof: VALUBusy 17-27%, HBM ~0%, occupancy 85% => load-latency
// bound (1 global load per FMA, single accumulator chain). Fix: stage input
// tiles in LDS (double-buffered, zero-padded halo), 16 oc-accumulators per
// thread => 16 FMAs per LDS read, weights via uniform scalar loads.
// Batch is chunked to fit ws_size (9 MiB/sample scratch).
// ---------------------------------------------------------------------------

static constexpr int NPOS  = 131072;        // 32*64*64 positions at VQ
static constexpr long long NELEM = 8388608; // NPOS * 64

// ======== 3x3 s1 p1 conv at 64x64, OCB=16 ==================================
// WMODE 0: w (OC,IC,3,3).  WMODE 1 (transposed): w (IC,OC,3,3), kernel flipped.
template<int IC, int OC, int WMODE, bool BIAS, bool RELU_IN, bool RELU_OUT>
__global__ void __launch_bounds__(256) conv3_t(
    const float* __restrict__ in, const float* __restrict__ w,
    const float* __restrict__ bias, float* __restrict__ out)
{
  constexpr int OCB = 16;
  __shared__ float lds[2][6 * 66];
  int tid = threadIdx.x;
  int r = tid >> 6, c = tid & 63;       // 4 rows x 64 cols per block
  int ty  = blockIdx.x * 4;             // tile top output row
  int oc0 = blockIdx.y * OCB;
  int b   = blockIdx.z;

  const float* inb = in + (size_t)b * IC * 4096;
  float acc[OCB];
  #pragma unroll
  for (int o = 0; o < OCB; ++o) acc[o] = BIAS ? bias[oc0 + o] : 0.f;

  for (int ic = 0; ic < IC; ++ic) {
    float* buf = lds[ic & 1];
    const float* pl = inb + (size_t)ic * 4096;
    for (int idx = tid; idx < 396; idx += 256) {
      int rr = idx / 66, cc = idx - rr * 66;
      int iy = ty + rr - 1, ix = cc - 1;
      float v = 0.f;
      if (iy >= 0 && iy < 64 && ix >= 0 && ix < 64) {
        v = pl[iy * 64 + ix];
        if (RELU_IN) v = fmaxf(v, 0.f);
      }
      buf[idx] = v;
    }
    __syncthreads();

    float v[9];
    #pragma unroll
    for (int ky = 0; ky < 3; ++ky)
      #pragma unroll
      for (int kx = 0; kx < 3; ++kx)
        v[ky * 3 + kx] = buf[(r + ky) * 66 + c + kx];

    #pragma unroll
    for (int t = 0; t < 9; ++t) {
      int ky = t / 3, kx = t - ky * 3;
      #pragma unroll
      for (int o = 0; o < OCB; ++o) {
        float wt = (WMODE == 0)
          ? w[((size_t)(oc0 + o) * IC + ic) * 9 + t]
          : w[((size_t)ic * OC + (oc0 + o)) * 9 + (2 - ky) * 3 + (2 - kx)];
        acc[o] += v[t] * wt;
      }
    }
    // no trailing sync needed: next iter writes the other buffer; overwrite
    // of this buffer happens only after the next barrier.
  }

  float* ob = out + ((size_t)b * OC + oc0) * 4096 + (ty + r) * 64 + c;
  #pragma unroll
  for (int o = 0; o < OCB; ++o) {
    float a = acc[o];
    if (RELU_OUT) a = fmaxf(a, 0.f);
    ob[(size_t)o * 4096] = a;
  }
}

// ======== enc_c2: 4x4 s2 p1, in (b,64,128,128) -> out (b,128,64,64) ========
__global__ void __launch_bounds__(256) conv4s2_t(
    const float* __restrict__ in, const float* __restrict__ w,
    const float* __restrict__ bias, float* __restrict__ out)
{
  constexpr int IC = 64, OC = 128, OCB = 16;
  __shared__ float lds[2][10 * 130];
  int tid = threadIdx.x;
  int r = tid >> 6, c = tid & 63;       // 4 out rows x 64 out cols
  int ty  = blockIdx.x * 4;
  int oc0 = blockIdx.y * OCB;
  int b   = blockIdx.z;

  const float* inb = in + (size_t)b * IC * 16384;
  float acc[OCB];
  #pragma unroll
  for (int o = 0; o < OCB; ++o) acc[o] = bias[oc0 + o];

  for (int ic = 0; ic < IC; ++ic) {
    float* buf = lds[ic & 1];
    const float* pl = inb + (size_t)ic * 16384;
    for (int idx = tid; idx < 1300; idx += 256) {
      int rr = idx / 130, cc = idx - rr * 130;
      int iy = ty * 2 + rr - 1, ix = cc - 1;
      float v = 0.f;
      if (iy >= 0 && iy < 128 && ix >= 0 && ix < 128) v = pl[iy * 128 + ix];
      buf[idx] = v;
    }
    __syncthreads();

    float v[16];
    #pragma unroll
    for (int ky = 0; ky < 4; ++ky)
      #pragma unroll
      for (int kx = 0; kx < 4; ++kx)
        v[ky * 4 + kx] = buf[(2 * r + ky) * 130 + 2 * c + kx];

    #pragma unroll
    for (int t = 0; t < 16; ++t) {
      #pragma unroll
      for (int o = 0; o < OCB; ++o)
        acc[o] += v[t] * w[((size_t)(oc0 + o) * IC + ic) * 16 + t];
    }
  }

  float* ob = out + ((size_t)b * OC + oc0) * 4096 + (ty + r) * 64 + c;
  #pragma unroll
  for (int o = 0; o < OCB; ++o)
    ob[(size_t)o * 4096] = fmaxf(acc[o], 0.f);
}

// ======== enc_c1: 4x4 s2 p1, in (b,1,256,256) -> out (b,64,128,128) ========
__global__ void __launch_bounds__(256) enc1_t(
    const float* __restrict__ in, const float* __restrict__ w,
    const float* __restrict__ bias, float* __restrict__ out)
{
  constexpr int OCB = 16;
  int tid = threadIdx.x;
  int rr = tid >> 7, ox = tid & 127;    // 2 out rows x 128 out cols
  int oy  = blockIdx.x * 2 + rr;
  int oc0 = blockIdx.y * OCB;
  int b   = blockIdx.z;

  const float* pl = in + (size_t)b * 65536;
  float v[16];
  #pragma unroll
  for (int ky = 0; ky < 4; ++ky) {
    int iy = 2 * oy - 1 + ky;
    #pragma unroll
    for (int kx = 0; kx < 4; ++kx) {
      int ix = 2 * ox - 1 + kx;
      v[ky * 4 + kx] = (iy >= 0 && iy < 256 && ix >= 0 && ix < 256)
                       ? pl[iy * 256 + ix] : 0.f;
    }
  }
  float acc[OCB];
  #pragma unroll
  for (int o = 0; o < OCB; ++o) acc[o] = bias[oc0 + o];
  #pragma unroll
  for (int t = 0; t < 16; ++t)
    #pragma unroll
    for (int o = 0; o < OCB; ++o)
      acc[o] += v[t] * w[(size_t)(oc0 + o) * 16 + t];

  float* ob = out + ((size_t)b * 64 + oc0) * 16384 + oy * 128 + ox;
  #pragma unroll
  for (int o = 0; o < OCB; ++o)
    ob[(size_t)o * 16384] = fmaxf(acc[o], 0.f);
}

// ======== res tail: out = relu(x) + w2 @ h (1x1), OCB=8 ====================
__global__ void __launch_bounds__(256) res_add_k(
    const float* __restrict__ x, const float* __restrict__ h,
    const float* __restrict__ w2, float* __restrict__ out)
{
  int p   = blockIdx.x * 256 + threadIdx.x;
  int oc0 = blockIdx.y * 8;
  int b   = blockIdx.z;
  const float* xb = x + ((size_t)b * 128 + oc0) * 4096 + p;
  float acc[8];
  #pragma unroll
  for (int o = 0; o < 8; ++o) acc[o] = fmaxf(xb[(size_t)o * 4096], 0.f);
  const float* hb = h + (size_t)b * 64 * 4096 + p;
  for (int ic = 0; ic < 64; ++ic) {
    float v = hb[(size_t)ic * 4096];
    #pragma unroll
    for (int o = 0; o < 8; ++o)
      acc[o] += w2[(oc0 + o) * 64 + ic] * v;
  }
  float* ob = out + ((size_t)b * 128 + oc0) * 4096 + p;
  #pragma unroll
  for (int o = 0; o < 8; ++o) ob[(size_t)o * 4096] = acc[o];
}

// ======== dec_c2: transposed 4x4 s2 p1, (b,128,64,64) -> (b,64,128,128) ====
// input is pre-relu residual output; relu applied at stage time. relu out.
__global__ void __launch_bounds__(256) dec2_t(
    const float* __restrict__ in, const float* __restrict__ w,
    const float* __restrict__ bias, float* __restrict__ out)
{
  constexpr int IC = 128, OC = 64, OCB = 16;
  __shared__ float lds[2][3 * 66];
  int tid = threadIdx.x;
  int rr = tid >> 7, ox = tid & 127;    // 2 out rows x 128 out cols
  int t   = blockIdx.x;                 // input center row; out rows 2t,2t+1
  int oc0 = blockIdx.y * OCB;
  int b   = blockIdx.z;

  int u  = ox >> 1, cc = ox & 1;
  int kyA = 1 - rr, kyB = kyA + 2;
  int rowA = 1 + rr, rowB = rr;
  int kxA = 1 - cc, kxB = kxA + 2;
  int colA = u + 1 + cc, colB = u + cc;

  const float* inb = in + (size_t)b * IC * 4096;
  float acc[OCB];
  #pragma unroll
  for (int o = 0; o < OCB; ++o) acc[o] = bias[oc0 + o];

  for (int ic = 0; ic < IC; ++ic) {
    float* buf = lds[ic & 1];
    const float* pl = inb + (size_t)ic * 4096;
    for (int idx = tid; idx < 198; idx += 256) {
      int r2 = idx / 66, c2 = idx - r2 * 66;
      int iy = t + r2 - 1, ix = c2 - 1;
      float v = 0.f;
      if (iy >= 0 && iy < 64 && ix >= 0 && ix < 64)
        v = fmaxf(pl[iy * 64 + ix], 0.f);
      buf[idx] = v;
    }
    __syncthreads();

    float vAA = buf[rowA * 66 + colA];
    float vAB = buf[rowA * 66 + colB];
    float vBA = buf[rowB * 66 + colA];
    float vBB = buf[rowB * 66 + colB];
    const float* wp = w + (size_t)ic * OC * 16;
    #pragma unroll
    for (int o = 0; o < OCB; ++o) {
      const float* wo = wp + (size_t)(oc0 + o) * 16;
      acc[o] += vAA * wo[kyA * 4 + kxA] + vAB * wo[kyA * 4 + kxB]
              + vBA * wo[kyB * 4 + kxA] + vBB * wo[kyB * 4 + kxB];
    }
  }

  int oy = 2 * t + rr;
  float* ob = out + ((size_t)b * OC + oc0) * 16384 + oy * 128 + ox;
  #pragma unroll
  for (int o = 0; o < OCB; ++o)
    ob[(size_t)o * 16384] = fmaxf(acc[o], 0.f);
}

// ======== dec_c3: transposed 4x4 s2 p1, (b,64,128,128) -> (b,1,256,256) ====
// OC=1: each thread computes a 2x2 output block; tanh epilogue.
__global__ void __launch_bounds__(256) dec3_t(
    const float* __restrict__ in, const float* __restrict__ w,
    const float* __restrict__ bias, float* __restrict__ out)
{
  __shared__ float lds[2][4 * 130];
  int tid = threadIdx.x;
  int yr = tid >> 7, x = tid & 127;     // 2 y-rows x 128 x-cols (input-res grid)
  int y0 = blockIdx.x * 2;
  int y  = y0 + yr;
  int b  = blockIdx.z;

  // tap tables: output row 2y+ry uses (ky, v-row dy): ry=0 -> (1,1),(3,0);
  // ry=1 -> (0,2),(2,1). Same pattern in x.
  const int kt[2][2] = {{1, 3}, {0, 2}};
  const int dt[2][2] = {{1, 0}, {2, 1}};

  const float* inb = in + (size_t)b * 64 * 16384;
  float acc[4] = {0.f, 0.f, 0.f, 0.f};

  for (int ic = 0; ic < 64; ++ic) {
    float* buf = lds[ic & 1];
    const float* pl = inb + (size_t)ic * 16384;
    for (int idx = tid; idx < 520; idx += 256) {
      int r2 = idx / 130, c2 = idx - r2 * 130;
      int iy = y0 + r2 - 1, ix = c2 - 1;
      float v = 0.f;
      if (iy >= 0 && iy < 128 && ix >= 0 && ix < 128) v = pl[iy * 128 + ix];
      buf[idx] = v;
    }
    __syncthreads();

    float v[9];
    #pragma unroll
    for (int dy = 0; dy < 3; ++dy)
      #pragma unroll
      for (int dx = 0; dx < 3; ++dx)
        v[dy * 3 + dx] = buf[(yr + dy) * 130 + x + dx];

    const float* wp = w + (size_t)ic * 16;
    #pragma unroll
    for (int ry = 0; ry < 2; ++ry)
      #pragma unroll
      for (int rx = 0; rx < 2; ++rx)
        #pragma unroll
        for (int a = 0; a < 2; ++a)
          #pragma unroll
          for (int c2 = 0; c2 < 2; ++c2)
            acc[ry * 2 + rx] += v[dt[ry][a] * 3 + dt[rx][c2]]
                              * wp[kt[ry][a] * 4 + kt[rx][c2]];
  }

  float b0 = bias[0];
  float* ob = out + (size_t)b * 65536;
  #pragma unroll
  for (int ry = 0; ry < 2; ++ry)
    #pragma unroll
    for (int rx = 0; rx < 2; ++rx)
      ob[(2 * y + ry) * 256 + 2 * x + rx] = tanhf(acc[ry * 2 + rx] + b0);
}

// ======== fused pre-VQ 1x1 conv + VQ =======================================
__global__ void __launch_bounds__(256) vq_k(
    const float* __restrict__ xres, const float* __restrict__ vw,
    const float* __restrict__ vb, const float* __restrict__ emb,
    float* __restrict__ qn, float* __restrict__ sum_sq, int* __restrict__ hist)
{
  int tid = threadIdx.x;
  int n = blockIdx.x * 256 + tid;
  int b = n >> 12;
  int pos = n & 4095;

  float z[64];
  #pragma unroll
  for (int k = 0; k < 64; ++k) z[k] = vb[k];

  const float* xb = xres + (size_t)b * 128 * 4096 + pos;
  for (int c = 0; c < 128; ++c) {
    float v = fmaxf(xb[(size_t)c * 4096], 0.f);
    #pragma unroll
    for (int k = 0; k < 64; ++k) z[k] += v * vw[k * 128 + c];
  }

  float z2 = 0.f;
  #pragma unroll
  for (int d = 0; d < 64; ++d) z2 += z[d] * z[d];

  float best = INFINITY;
  int bidx = 0;
  for (int k = 0; k < 64; ++k) {
    float dot = 0.f, e2 = 0.f;
    #pragma unroll
    for (int d = 0; d < 64; ++d) {
      float e = emb[k * 64 + d];
      dot += z[d] * e;
      e2  += e * e;
    }
    float dist = z2 + e2 - 2.f * dot;
    if (dist < best) { best = dist; bidx = k; }
  }

  float sq = 0.f;
  const float* eb = emb + bidx * 64;
  float* qb = qn + (size_t)b * 64 * 4096 + pos;
  #pragma unroll
  for (int d = 0; d < 64; ++d) {
    float e = eb[d];
    float df = e - z[d];
    sq += df * df;
    qb[(size_t)d * 4096] = e;
  }

  __shared__ float red[256];
  __shared__ int lh[64];
  red[tid] = sq;
  if (tid < 64) lh[tid] = 0;
  __syncthreads();
  atomicAdd(&lh[bidx], 1);
  for (int s = 128; s > 0; s >>= 1) {
    if (tid < s) red[tid] += red[tid + s];
    __syncthreads();
  }
  if (tid == 0) atomicAdd(sum_sq, red[0]);
  if (tid < 64) atomicAdd(&hist[tid], lh[tid]);
}

// ======== scratch init + scalar finalize ===================================
__global__ void init_k(float* sum_sq, int* hist)
{
  int t = threadIdx.x;
  if (t == 0) sum_sq[0] = 0.f;
  if (t < 64) hist[t] = 0;
}

__global__ void finalize_k(const float* __restrict__ sum_sq, const int* __restrict__ hist,
                           float* __restrict__ loss_out, float* __restrict__ perp_out)
{
  if (threadIdx.x == 0) {
    float mse = sum_sq[0] / (float)NELEM;
    loss_out[0] = 1.25f * mse;
    float ent = 0.f;
    for (int k = 0; k < 64; ++k) {
      float p = (float)hist[k] / (float)NPOS;
      ent += p * logf(p + 1e-10f);
    }
    perp_out[0] = expf(-ent);
  }
}

// ---------------------------------------------------------------------------
extern "C" void kernel_launch(void* const* d_in, const int* in_sizes, int n_in,
                              void* d_out, int out_size, void* d_ws, size_t ws_size,
                              hipStream_t stream)
{
  const float* x        = (const float*)d_in[0];
  const float* enc_c1_w = (const float*)d_in[1];
  const float* enc_c1_b = (const float*)d_in[2];
  const float* enc_c2_w = (const float*)d_in[3];
  const float* enc_c2_b = (const float*)d_in[4];
  const float* enc_c3_w = (const float*)d_in[5];
  const float* enc_c3_b = (const float*)d_in[6];
  const float* enc_r1_w = (const float*)d_in[7];
  const float* enc_r2_w = (const float*)d_in[8];
  const float* vqc_w    = (const float*)d_in[9];
  const float* vqc_b    = (const float*)d_in[10];
  const float* emb      = (const float*)d_in[11];
  const float* dec_c1_w = (const float*)d_in[12];
  const float* dec_c1_b = (const float*)d_in[13];
  const float* dec_r1_w = (const float*)d_in[14];
  const float* dec_r2_w = (const float*)d_in[15];
  const float* dec_c2_w = (const float*)d_in[16];
  const float* dec_c2_b = (const float*)d_in[17];
  const float* dec_c3_w = (const float*)d_in[18];
  const float* dec_c3_b = (const float*)d_in[19];

  // output: [loss(1)] [x_re(32*65536)] [perplexity(1)] [qn(32*262144)]
  float* out      = (float*)d_out;
  float* loss_out = out;
  float* xre_out  = out + 1;
  float* perp_out = out + 1 + 2097152;
  float* qn_out   = out + 2 + 2097152;

  float* sum_sq = (float*)d_ws;
  int*   hist   = (int*)d_ws + 1;
  float* base   = (float*)d_ws + 256;

  const size_t PER_A = 1048576, PER_B = 524288, PER_D = 262144;
  const size_t PER_SAMPLE = PER_A + 2 * PER_B + PER_D;  // 9 MiB

  long long avail = (long long)(ws_size / 4) - 256;
  int chunk = (int)(avail / (long long)PER_SAMPLE);
  if (chunk > 32) chunk = 32;
  if (chunk < 1)  chunk = 1;

  hipLaunchKernelGGL(init_k, dim3(1), dim3(128), 0, stream, sum_sq, hist);

  for (int b0 = 0; b0 < 32; b0 += chunk) {
    int cur = (32 - b0 < chunk) ? (32 - b0) : chunk;

    float* A = base;
    float* B = A + (size_t)chunk * PER_A;
    float* C = B + (size_t)chunk * PER_B;
    float* D = C + (size_t)chunk * PER_B;

    const float* xC  = x + (size_t)b0 * 65536;
    float* qnC  = qn_out + (size_t)b0 * 262144;
    float* xreC = xre_out + (size_t)b0 * 65536;

    // ---- encoder ----
    hipLaunchKernelGGL(enc1_t, dim3(64, 4, cur), dim3(256), 0, stream,
                       xC, enc_c1_w, enc_c1_b, A);
    hipLaunchKernelGGL(conv4s2_t, dim3(16, 8, cur), dim3(256), 0, stream,
                       A, enc_c2_w, enc_c2_b, B);
    hipLaunchKernelGGL((conv3_t<128, 128, 0, true, false, false>),
                       dim3(16, 8, cur), dim3(256), 0, stream,
                       B, enc_c3_w, enc_c3_b, C);

    // encoder residual block (2 iters, shared weights)
    hipLaunchKernelGGL((conv3_t<128, 64, 0, false, true, true>),
                       dim3(16, 4, cur), dim3(256), 0, stream,
                       C, enc_r1_w, nullptr, D);
    hipLaunchKernelGGL(res_add_k, dim3(16, 16, cur), dim3(256), 0, stream,
                       C, D, enc_r2_w, B);
    hipLaunchKernelGGL((conv3_t<128, 64, 0, false, true, true>),
                       dim3(16, 4, cur), dim3(256), 0, stream,
                       B, enc_r1_w, nullptr, D);
    hipLaunchKernelGGL(res_add_k, dim3(16, 16, cur), dim3(256), 0, stream,
                       B, D, enc_r2_w, C);

    // ---- fused pre-VQ conv + VQ (final res relu applied on read) ----
    hipLaunchKernelGGL(vq_k, dim3(cur * 16), dim3(256), 0, stream,
                       C, vqc_w, vqc_b, emb, qnC, sum_sq, hist);

    // ---- decoder ----
    hipLaunchKernelGGL((conv3_t<64, 128, 1, true, false, false>),
                       dim3(16, 8, cur), dim3(256), 0, stream,
                       qnC, dec_c1_w, dec_c1_b, B);

    hipLaunchKernelGGL((conv3_t<128, 64, 0, false, true, true>),
                       dim3(16, 4, cur), dim3(256), 0, stream,
                       B, dec_r1_w, nullptr, D);
    hipLaunchKernelGGL(res_add_k, dim3(16, 16, cur), dim3(256), 0, stream,
                       B, D, dec_r2_w, C);
    hipLaunchKernelGGL((conv3_t<128, 64, 0, false, true, true>),
                       dim3(16, 4, cur), dim3(256), 0, stream,
                       C, dec_r1_w, nullptr, D);
    hipLaunchKernelGGL(res_add_k, dim3(16, 16, cur), dim3(256), 0, stream,
                       C, D, dec_r2_w, B);

    // dec_c2 (relu of residual applied at stage time), relu out
    hipLaunchKernelGGL(dec2_t, dim3(64, 4, cur), dim3(256), 0, stream,
                       B, dec_c2_w, dec_c2_b, A);
    hipLaunchKernelGGL(dec3_t, dim3(64, 1, cur), dim3(256), 0, stream,
                       A, dec_c3_w, dec_c3_b, xreC);
  }

  hipLaunchKernelGGL(finalize_k, dim3(1), dim3(64), 0, stream,
                     sum_sq, hist, loss_out, perp_out);
}